// Round 1
// baseline (455.768 us; speedup 1.0000x reference)
//
#include <hip/hip_runtime.h>
#include <float.h>
#include <math.h>

#define D 128
#define FIVE_D 640
#define NOUT 128
#define ROWS 8

// ---------------- Kernel 1: segment offsets via binary search on sorted batch ----------------
__global__ void seg_offsets_kernel(const int* __restrict__ batch, int* __restrict__ offs,
                                   int N, int G) {
    int g = blockIdx.x * blockDim.x + threadIdx.x;
    if (g > G) return;
    if (g == G) { offs[G] = N; return; }
    // lower_bound: first index i with batch[i] >= g
    int lo = 0, hi = N;
    while (lo < hi) {
        int mid = (lo + hi) >> 1;
        if (batch[mid] < g) lo = mid + 1; else hi = mid;
    }
    offs[g] = lo;
}

// ---------------- Kernel 2: per-segment stats -> feats[g][640] ----------------
// One wave (64 lanes) per segment. Lane owns features 2*lane, 2*lane+1 (float2 loads).
__global__ __launch_bounds__(64) void seg_stats_kernel(const float* __restrict__ x,
                                                       const int* __restrict__ offs,
                                                       float* __restrict__ feats) {
    const int g = blockIdx.x;
    const int lane = threadIdx.x;
    const int start = offs[g];
    const int end   = offs[g + 1];

    float sx = 0.f, sy = 0.f, qx = 0.f, qy = 0.f;
    float mnx = FLT_MAX, mny = FLT_MAX, mxx = -FLT_MAX, mxy = -FLT_MAX;

    const float2* xp = reinterpret_cast<const float2*>(x) + lane;  // row r at xp[r*64]

    int r = start;
    for (; r + 2 <= end; r += 2) {
        float2 v0 = xp[r * 64];
        float2 v1 = xp[(r + 1) * 64];
        sx += v0.x; sy += v0.y;
        qx = fmaf(v0.x, v0.x, qx); qy = fmaf(v0.y, v0.y, qy);
        mnx = fminf(mnx, v0.x); mny = fminf(mny, v0.y);
        mxx = fmaxf(mxx, v0.x); mxy = fmaxf(mxy, v0.y);
        sx += v1.x; sy += v1.y;
        qx = fmaf(v1.x, v1.x, qx); qy = fmaf(v1.y, v1.y, qy);
        mnx = fminf(mnx, v1.x); mny = fminf(mny, v1.y);
        mxx = fmaxf(mxx, v1.x); mxy = fmaxf(mxy, v1.y);
    }
    if (r < end) {
        float2 v0 = xp[r * 64];
        sx += v0.x; sy += v0.y;
        qx = fmaf(v0.x, v0.x, qx); qy = fmaf(v0.y, v0.y, qy);
        mnx = fminf(mnx, v0.x); mny = fminf(mny, v0.y);
        mxx = fmaxf(mxx, v0.x); mxy = fmaxf(mxy, v0.y);
    }

    const float cnt = (float)max(end - start, 1);
    const float inv = 1.0f / cnt;
    const float meanx = sx * inv, meany = sy * inv;
    const float msqx = qx * inv, msqy = qy * inv;
    const float stdx = sqrtf(fmaxf(msqx - meanx * meanx, 1e-9f));
    const float stdy = sqrtf(fmaxf(msqy - meany * meany, 1e-9f));
    const float SC = 0.14142135623730950488f;  // 1/sqrt(AVG_NODES=50)

    float* f = feats + (size_t)g * FIVE_D + 2 * lane;
    f[0]         = sx * SC;  f[1]         = sy * SC;
    f[D]         = meanx;    f[D + 1]     = meany;
    f[2 * D]     = mnx;      f[2 * D + 1] = mny;
    f[3 * D]     = mxx;      f[3 * D + 1] = mxy;
    f[4 * D]     = stdx;     f[4 * D + 1] = stdy;
}

// ---------------- Kernel 3: out[G,128] = feats[G,640] @ W[640,128] + b ----------------
// 64-thread block handles ROWS rows x 128 cols; lane owns cols (lane, lane+64).
__global__ __launch_bounds__(64) void gemm_kernel(const float* __restrict__ feats,
                                                  const float* __restrict__ W,
                                                  const float* __restrict__ b,
                                                  float* __restrict__ out, int G) {
    __shared__ float lf[ROWS * FIVE_D];
    const int g0 = blockIdx.x * ROWS;
    const int lane = threadIdx.x;

    // Stage feats tile into LDS (ROWS*640 floats = 1280 float4).
    {
        const float4* src = reinterpret_cast<const float4*>(feats + (size_t)g0 * FIVE_D);
        float4* dst = reinterpret_cast<float4*>(lf);
        #pragma unroll
        for (int i = 0; i < (ROWS * FIVE_D) / 4 / 64; ++i)
            dst[i * 64 + lane] = src[i * 64 + lane];
    }
    __syncthreads();

    float acc0[ROWS], acc1[ROWS];
    #pragma unroll
    for (int r = 0; r < ROWS; ++r) { acc0[r] = 0.f; acc1[r] = 0.f; }

    for (int k = 0; k < FIVE_D; k += 4) {
        const float w00 = W[(k + 0) * NOUT + lane];
        const float w10 = W[(k + 0) * NOUT + 64 + lane];
        const float w01 = W[(k + 1) * NOUT + lane];
        const float w11 = W[(k + 1) * NOUT + 64 + lane];
        const float w02 = W[(k + 2) * NOUT + lane];
        const float w12 = W[(k + 2) * NOUT + 64 + lane];
        const float w03 = W[(k + 3) * NOUT + lane];
        const float w13 = W[(k + 3) * NOUT + 64 + lane];
        #pragma unroll
        for (int r = 0; r < ROWS; ++r) {
            const float4 f = *reinterpret_cast<const float4*>(&lf[r * FIVE_D + k]);
            acc0[r] = fmaf(f.x, w00, acc0[r]); acc1[r] = fmaf(f.x, w10, acc1[r]);
            acc0[r] = fmaf(f.y, w01, acc0[r]); acc1[r] = fmaf(f.y, w11, acc1[r]);
            acc0[r] = fmaf(f.z, w02, acc0[r]); acc1[r] = fmaf(f.z, w12, acc1[r]);
            acc0[r] = fmaf(f.w, w03, acc0[r]); acc1[r] = fmaf(f.w, w13, acc1[r]);
        }
    }

    const float b0 = b[lane];
    const float b1 = b[64 + lane];
    #pragma unroll
    for (int r = 0; r < ROWS; ++r) {
        const int g = g0 + r;
        if (g < G) {
            out[(size_t)g * NOUT + lane]      = acc0[r] + b0;
            out[(size_t)g * NOUT + 64 + lane] = acc1[r] + b1;
        }
    }
}

extern "C" void kernel_launch(void* const* d_in, const int* in_sizes, int n_in,
                              void* d_out, int out_size, void* d_ws, size_t ws_size,
                              hipStream_t stream) {
    const float* x     = (const float*)d_in[0];
    const int*   batch = (const int*)d_in[1];
    const float* W     = (const float*)d_in[2];
    const float* b     = (const float*)d_in[3];
    // d_in[4] = num_segments (scalar) — value known from out_size
    float* out = (float*)d_out;

    const int N = in_sizes[0] / D;       // 500000
    const int G = out_size / NOUT;       // 10000

    int*   offs  = (int*)d_ws;                               // (G+1) ints
    float* feats = (float*)((char*)d_ws + 65536);            // G * 640 floats

    seg_offsets_kernel<<<(G + 1 + 255) / 256, 256, 0, stream>>>(batch, offs, N, G);
    seg_stats_kernel<<<G, 64, 0, stream>>>(x, offs, feats);
    gemm_kernel<<<(G + ROWS - 1) / ROWS, 64, 0, stream>>>(feats, W, b, out, G);
}

// Round 2
// 425.490 us; speedup vs baseline: 1.0712x; 1.0712x over previous
//
#include <hip/hip_runtime.h>
#include <float.h>
#include <math.h>

#define D 128
#define FIVE_D 640
#define NOUT 128
#define GR 8  // gemm rows per block

// ---------------- Kernel 1: segment offsets via binary search on sorted batch ----------------
__global__ void seg_offsets_kernel(const int* __restrict__ batch, int* __restrict__ offs,
                                   int N, int G) {
    int g = blockIdx.x * blockDim.x + threadIdx.x;
    if (g > G) return;
    if (g == G) { offs[G] = N; return; }
    int lo = 0, hi = N;
    while (lo < hi) {
        int mid = (lo + hi) >> 1;
        if (batch[mid] < g) lo = mid + 1; else hi = mid;
    }
    offs[g] = lo;
}

// ---------------- Kernel 2: per-segment stats -> feats[g][640] ----------------
// One wave per segment. Lane (half,c): half=lane>>5 picks even/odd row of a 2-row
// step, c=lane&31 picks float4 column. 64 lanes x 16B = 1024B = 2 full rows per
// load instruction. Main loop keeps 4 float4 loads (8 rows) in flight per lane.
__global__ __launch_bounds__(64) void seg_stats_kernel(const float* __restrict__ x,
                                                       const int* __restrict__ offs,
                                                       float* __restrict__ feats) {
    const int g = blockIdx.x;
    const int lane = threadIdx.x;
    const int half = lane >> 5;
    const int c = lane & 31;
    const int start = offs[g];
    const int end   = offs[g + 1];

    float4 s  = make_float4(0.f, 0.f, 0.f, 0.f);
    float4 q  = make_float4(0.f, 0.f, 0.f, 0.f);
    float4 mn = make_float4(FLT_MAX, FLT_MAX, FLT_MAX, FLT_MAX);
    float4 mx = make_float4(-FLT_MAX, -FLT_MAX, -FLT_MAX, -FLT_MAX);

    const float4* xp = reinterpret_cast<const float4*>(x) + c;  // row r at xp[r*32]

    auto acc = [&](float4 v) {
        s.x += v.x; s.y += v.y; s.z += v.z; s.w += v.w;
        q.x = fmaf(v.x, v.x, q.x); q.y = fmaf(v.y, v.y, q.y);
        q.z = fmaf(v.z, v.z, q.z); q.w = fmaf(v.w, v.w, q.w);
        mn.x = fminf(mn.x, v.x); mn.y = fminf(mn.y, v.y);
        mn.z = fminf(mn.z, v.z); mn.w = fminf(mn.w, v.w);
        mx.x = fmaxf(mx.x, v.x); mx.y = fmaxf(mx.y, v.y);
        mx.z = fmaxf(mx.z, v.z); mx.w = fmaxf(mx.w, v.w);
    };

    int base = start;
    // main loop: 8 rows / iter, 4 independent float4 loads in flight
    for (; base + 8 <= end; base += 8) {
        float4 v0 = xp[(size_t)(base + 0 + half) * 32];
        float4 v1 = xp[(size_t)(base + 2 + half) * 32];
        float4 v2 = xp[(size_t)(base + 4 + half) * 32];
        float4 v3 = xp[(size_t)(base + 6 + half) * 32];
        acc(v0); acc(v1); acc(v2); acc(v3);
    }
    // 2-row cleanup
    for (; base + 2 <= end; base += 2) {
        float4 v = xp[(size_t)(base + half) * 32];
        acc(v);
    }
    // final odd row: handled by half==0 lanes only
    if (base < end && half == 0) {
        float4 v = xp[(size_t)base * 32];
        acc(v);
    }

    // combine the two halves (lane <-> lane^32)
    s.x += __shfl_xor(s.x, 32); s.y += __shfl_xor(s.y, 32);
    s.z += __shfl_xor(s.z, 32); s.w += __shfl_xor(s.w, 32);
    q.x += __shfl_xor(q.x, 32); q.y += __shfl_xor(q.y, 32);
    q.z += __shfl_xor(q.z, 32); q.w += __shfl_xor(q.w, 32);
    mn.x = fminf(mn.x, __shfl_xor(mn.x, 32)); mn.y = fminf(mn.y, __shfl_xor(mn.y, 32));
    mn.z = fminf(mn.z, __shfl_xor(mn.z, 32)); mn.w = fminf(mn.w, __shfl_xor(mn.w, 32));
    mx.x = fmaxf(mx.x, __shfl_xor(mx.x, 32)); mx.y = fmaxf(mx.y, __shfl_xor(mx.y, 32));
    mx.z = fmaxf(mx.z, __shfl_xor(mx.z, 32)); mx.w = fmaxf(mx.w, __shfl_xor(mx.w, 32));

    if (half == 0) {
        const float cnt = (float)max(end - start, 1);
        const float inv = 1.0f / cnt;
        const float SC = 0.14142135623730950488f;  // 1/sqrt(50)
        float4 mean = make_float4(s.x * inv, s.y * inv, s.z * inv, s.w * inv);
        float4 sd;
        sd.x = sqrtf(fmaxf(q.x * inv - mean.x * mean.x, 1e-9f));
        sd.y = sqrtf(fmaxf(q.y * inv - mean.y * mean.y, 1e-9f));
        sd.z = sqrtf(fmaxf(q.z * inv - mean.z * mean.z, 1e-9f));
        sd.w = sqrtf(fmaxf(q.w * inv - mean.w * mean.w, 1e-9f));
        float4 ssc = make_float4(s.x * SC, s.y * SC, s.z * SC, s.w * SC);

        float* f = feats + (size_t)g * FIVE_D + 4 * c;
        *reinterpret_cast<float4*>(f)         = ssc;
        *reinterpret_cast<float4*>(f + D)     = mean;
        *reinterpret_cast<float4*>(f + 2 * D) = mn;
        *reinterpret_cast<float4*>(f + 3 * D) = mx;
        *reinterpret_cast<float4*>(f + 4 * D) = sd;
    }
}

// ---------------- Kernel 3: out[G,128] = feats[G,640] @ W[640,128] + b ----------------
// 256 threads (4 waves) per block, GR=8 rows. Wave w owns rows {2w, 2w+1};
// lane owns cols (lane, lane+64). feats tile staged in LDS (broadcast reads).
__global__ __launch_bounds__(256) void gemm_kernel(const float* __restrict__ feats,
                                                   const float* __restrict__ W,
                                                   const float* __restrict__ b,
                                                   float* __restrict__ out, int G) {
    __shared__ float lf[GR * FIVE_D];
    const int tid = threadIdx.x;
    const int lane = tid & 63;
    const int wave = tid >> 6;
    const int g0 = blockIdx.x * GR;

    {
        const float4* src = reinterpret_cast<const float4*>(feats + (size_t)g0 * FIVE_D);
        float4* dst = reinterpret_cast<float4*>(lf);
        #pragma unroll
        for (int i = 0; i < (GR * FIVE_D) / 4 / 256; ++i)  // 5
            dst[i * 256 + tid] = src[i * 256 + tid];
    }
    __syncthreads();

    const int r0 = wave * 2, r1 = wave * 2 + 1;
    float a00 = 0.f, a01 = 0.f, a10 = 0.f, a11 = 0.f;

    for (int k = 0; k < FIVE_D; k += 4) {
        const float w00 = W[(k + 0) * NOUT + lane];
        const float w01 = W[(k + 0) * NOUT + 64 + lane];
        const float w10 = W[(k + 1) * NOUT + lane];
        const float w11 = W[(k + 1) * NOUT + 64 + lane];
        const float w20 = W[(k + 2) * NOUT + lane];
        const float w21 = W[(k + 2) * NOUT + 64 + lane];
        const float w30 = W[(k + 3) * NOUT + lane];
        const float w31 = W[(k + 3) * NOUT + 64 + lane];
        const float4 f0 = *reinterpret_cast<const float4*>(&lf[r0 * FIVE_D + k]);
        const float4 f1 = *reinterpret_cast<const float4*>(&lf[r1 * FIVE_D + k]);
        a00 = fmaf(f0.x, w00, a00); a01 = fmaf(f0.x, w01, a01);
        a10 = fmaf(f1.x, w00, a10); a11 = fmaf(f1.x, w01, a11);
        a00 = fmaf(f0.y, w10, a00); a01 = fmaf(f0.y, w11, a01);
        a10 = fmaf(f1.y, w10, a10); a11 = fmaf(f1.y, w11, a11);
        a00 = fmaf(f0.z, w20, a00); a01 = fmaf(f0.z, w21, a01);
        a10 = fmaf(f1.z, w20, a10); a11 = fmaf(f1.z, w21, a11);
        a00 = fmaf(f0.w, w30, a00); a01 = fmaf(f0.w, w31, a01);
        a10 = fmaf(f1.w, w30, a10); a11 = fmaf(f1.w, w31, a11);
    }

    const float b0 = b[lane];
    const float b1 = b[64 + lane];
    if (g0 + r0 < G) {
        out[(size_t)(g0 + r0) * NOUT + lane]      = a00 + b0;
        out[(size_t)(g0 + r0) * NOUT + 64 + lane] = a01 + b1;
    }
    if (g0 + r1 < G) {
        out[(size_t)(g0 + r1) * NOUT + lane]      = a10 + b0;
        out[(size_t)(g0 + r1) * NOUT + 64 + lane] = a11 + b1;
    }
}

extern "C" void kernel_launch(void* const* d_in, const int* in_sizes, int n_in,
                              void* d_out, int out_size, void* d_ws, size_t ws_size,
                              hipStream_t stream) {
    const float* x     = (const float*)d_in[0];
    const int*   batch = (const int*)d_in[1];
    const float* W     = (const float*)d_in[2];
    const float* b     = (const float*)d_in[3];
    float* out = (float*)d_out;

    const int N = in_sizes[0] / D;       // 500000
    const int G = out_size / NOUT;       // 10000

    int*   offs  = (int*)d_ws;                               // (G+1) ints
    float* feats = (float*)((char*)d_ws + 65536);            // G * 640 floats

    seg_offsets_kernel<<<(G + 1 + 255) / 256, 256, 0, stream>>>(batch, offs, N, G);
    seg_stats_kernel<<<G, 64, 0, stream>>>(x, offs, feats);
    gemm_kernel<<<(G + GR - 1) / GR, 256, 0, stream>>>(feats, W, b, out, G);
}